// Round 8
// baseline (640.511 us; speedup 1.0000x reference)
//
#include <hip/hip_runtime.h>
#include <math.h>

namespace {

constexpr int B  = 2;
constexpr int N  = 1024;
constexpr int CF = 64;    // C_FEAT
constexpr int S  = 512;
constexpr int K  = 32;
constexpr int DM = 128;   // D_MODEL
constexpr int NH = 4;
constexpr int DH = 32;
constexpr int GC = 67;    // grouped channels = CF + 3
constexpr int DIN = 131;  // GC + CF
constexpr int DPAD = 132; // padded row for float4 LDS reads
constexpr int EPAD = 516; // S+4: keeps e rows 16B-aligned for float4 reads

typedef float f2 __attribute__((ext_vector_type(2)));

// DPP helpers. Reduce-to-lane63 pattern: row_shr:1/2/4/8, row_bcast:15, row_bcast:31.
template <int CTRL>
__device__ inline float dpp_mov_f(float v) {
  // bound_ctrl=true: invalid lanes read 0 — valid identity for fmax of nonneg values.
  return __int_as_float(__builtin_amdgcn_update_dpp(0, __float_as_int(v), CTRL, 0xF, 0xF, true));
}
template <int CTRL>
__device__ inline unsigned dpp_mov_self_u(unsigned v) {
  // bound_ctrl=false with old=v: invalid lanes yield v — identity for min.
  return (unsigned)__builtin_amdgcn_update_dpp((int)v, (int)v, CTRL, 0xF, 0xF, false);
}

// ---------------- FPS: BOTH batches in ONE wave (interleaved serial chains) ----------------
// Two independent FPS chains issue back-to-back each step; each chain's
// latency stalls (LDS centroid read, DPP reduce chain) are hidden by the
// other's issue. Per batch: r4's verified two-pass argmax (f32 DPP max,
// then min-index among exact maxima -> jnp.argmax first-occurrence ties).
// Distance update via float2 ext-vectors -> v_pk_* packed f32 where the
// backend supports it (identical per-element rounding either way).
__global__ void __launch_bounds__(64, 1)
fps_kernel(const float* __restrict__ xyz, int* __restrict__ fps_idx,
           float* __restrict__ new_xyz) {
  const int lane = threadIdx.x;           // 64 threads = 1 wave, grid = 1
  __shared__ __align__(16) float4 pts4[B][N];
  __shared__ int farhist[B][S];
  for (int p = lane; p < B*N; p += 64) {
    const int bb = p >> 10, pp = p & (N-1);
    pts4[bb][pp] = make_float4(xyz[bb*N*3 + pp*3+0], xyz[bb*N*3 + pp*3+1],
                               xyz[bb*N*3 + pp*3+2], 0.0f);
  }
  __syncthreads();
  // slot k (0..15) holds point k*64+lane; f2 slot j packs k=2j (.x), 2j+1 (.y)
  f2 X0[8], Y0[8], Z0[8], X1[8], Y1[8], Z1[8];
  float d0[16], d1[16];
  #pragma unroll
  for (int j = 0; j < 8; ++j) {
    const float4 a0 = pts4[0][(2*j)*64 + lane];
    const float4 b0 = pts4[0][(2*j+1)*64 + lane];
    X0[j] = f2{a0.x, b0.x}; Y0[j] = f2{a0.y, b0.y}; Z0[j] = f2{a0.z, b0.z};
    const float4 a1 = pts4[1][(2*j)*64 + lane];
    const float4 b1 = pts4[1][(2*j+1)*64 + lane];
    X1[j] = f2{a1.x, b1.x}; Y1[j] = f2{a1.y, b1.y}; Z1[j] = f2{a1.z, b1.z};
  }
  #pragma unroll
  for (int k = 0; k < 16; ++k) { d0[k] = 1e10f; d1[k] = 1e10f; }
  int far0 = 0, far1 = 0;
  for (int s = 0; s < S; ++s) {
    if (lane == 0) { farhist[0][s] = far0; farhist[1][s] = far1; }
    const float4 c0 = pts4[0][far0];
    const float4 c1 = pts4[1][far1];
    const f2 cx0 = f2{c0.x, c0.x}, cy0 = f2{c0.y, c0.y}, cz0 = f2{c0.z, c0.z};
    const f2 cx1 = f2{c1.x, c1.x}, cy1 = f2{c1.y, c1.y}, cz1 = f2{c1.z, c1.z};
    // distance update, both batches (same expression form as reference)
    #pragma unroll
    for (int j = 0; j < 8; ++j) {
      {
        const f2 dx = X0[j] - cx0, dy = Y0[j] - cy0, dz = Z0[j] - cz0;
        const f2 q = dx*dx + dy*dy + dz*dz;
        d0[2*j]   = fminf(d0[2*j],   q.x);
        d0[2*j+1] = fminf(d0[2*j+1], q.y);
      }
      {
        const f2 dx = X1[j] - cx1, dy = Y1[j] - cy1, dz = Z1[j] - cz1;
        const f2 q = dx*dx + dy*dy + dz*dz;
        d1[2*j]   = fminf(d1[2*j],   q.x);
        d1[2*j+1] = fminf(d1[2*j+1], q.y);
      }
    }
    // pass 1: lane-local max trees, both batches
    float m0[8], m1[8];
    #pragma unroll
    for (int j = 0; j < 8; ++j) { m0[j] = fmaxf(d0[j], d0[j+8]); m1[j] = fmaxf(d1[j], d1[j+8]); }
    #pragma unroll
    for (int j = 0; j < 4; ++j) { m0[j] = fmaxf(m0[j], m0[j+4]); m1[j] = fmaxf(m1[j], m1[j+4]); }
    float mv0 = fmaxf(fmaxf(m0[0], m0[2]), fmaxf(m0[1], m0[3]));
    float mv1 = fmaxf(fmaxf(m1[0], m1[2]), fmaxf(m1[1], m1[3]));
    // wave64 max via DPP (two independent chains interleave)
    mv0 = fmaxf(mv0, dpp_mov_f<0x111>(mv0));  mv1 = fmaxf(mv1, dpp_mov_f<0x111>(mv1));
    mv0 = fmaxf(mv0, dpp_mov_f<0x112>(mv0));  mv1 = fmaxf(mv1, dpp_mov_f<0x112>(mv1));
    mv0 = fmaxf(mv0, dpp_mov_f<0x114>(mv0));  mv1 = fmaxf(mv1, dpp_mov_f<0x114>(mv1));
    mv0 = fmaxf(mv0, dpp_mov_f<0x118>(mv0));  mv1 = fmaxf(mv1, dpp_mov_f<0x118>(mv1));
    mv0 = fmaxf(mv0, dpp_mov_f<0x142>(mv0));  mv1 = fmaxf(mv1, dpp_mov_f<0x142>(mv1));
    mv0 = fmaxf(mv0, dpp_mov_f<0x143>(mv0));  mv1 = fmaxf(mv1, dpp_mov_f<0x143>(mv1));
    const float maxv0 = __int_as_float(__builtin_amdgcn_readlane(__float_as_int(mv0), 63));
    const float maxv1 = __int_as_float(__builtin_amdgcn_readlane(__float_as_int(mv1), 63));
    // pass 2: min index among exact maxima, both batches
    unsigned c0n[16], c1n[16];
    #pragma unroll
    for (int k = 0; k < 16; ++k) {
      c0n[k] = (d0[k] == maxv0) ? (unsigned)(k*64 + lane) : 0xFFFFFFFFu;
      c1n[k] = (d1[k] == maxv1) ? (unsigned)(k*64 + lane) : 0xFFFFFFFFu;
    }
    #pragma unroll
    for (int k = 0; k < 8; ++k) { c0n[k] = min(c0n[k], c0n[k+8]); c1n[k] = min(c1n[k], c1n[k+8]); }
    #pragma unroll
    for (int k = 0; k < 4; ++k) { c0n[k] = min(c0n[k], c0n[k+4]); c1n[k] = min(c1n[k], c1n[k+4]); }
    unsigned cand0 = min(min(c0n[0], c0n[2]), min(c0n[1], c0n[3]));
    unsigned cand1 = min(min(c1n[0], c1n[2]), min(c1n[1], c1n[3]));
    cand0 = min(cand0, dpp_mov_self_u<0x111>(cand0));  cand1 = min(cand1, dpp_mov_self_u<0x111>(cand1));
    cand0 = min(cand0, dpp_mov_self_u<0x112>(cand0));  cand1 = min(cand1, dpp_mov_self_u<0x112>(cand1));
    cand0 = min(cand0, dpp_mov_self_u<0x114>(cand0));  cand1 = min(cand1, dpp_mov_self_u<0x114>(cand1));
    cand0 = min(cand0, dpp_mov_self_u<0x118>(cand0));  cand1 = min(cand1, dpp_mov_self_u<0x118>(cand1));
    cand0 = min(cand0, dpp_mov_self_u<0x142>(cand0));  cand1 = min(cand1, dpp_mov_self_u<0x142>(cand1));
    cand0 = min(cand0, dpp_mov_self_u<0x143>(cand0));  cand1 = min(cand1, dpp_mov_self_u<0x143>(cand1));
    far0 = __builtin_amdgcn_readlane((int)cand0, 63);
    far1 = __builtin_amdgcn_readlane((int)cand1, 63);
  }
  __syncthreads();
  // epilogue: write fps_idx and new_xyz from history, both batches
  for (int s = lane; s < S; s += 64) {
    {
      const int f = farhist[0][s];
      const float4 c = pts4[0][f];
      fps_idx[s] = f;
      new_xyz[s*3+0] = c.x; new_xyz[s*3+1] = c.y; new_xyz[s*3+2] = c.z;
    }
    {
      const int f = farhist[1][s];
      const float4 c = pts4[1][f];
      fps_idx[S+s] = f;
      new_xyz[(S+s)*3+0] = c.x; new_xyz[(S+s)*3+1] = c.y; new_xyz[(S+s)*3+2] = c.z;
    }
  }
}

// ---------------- KNN (K=32 of N=1024), one wave per query ----------------
__global__ void knn_kernel(const float* __restrict__ xyz, const float* __restrict__ new_xyz,
                           int* __restrict__ knn_idx) {
  const int b = blockIdx.y;
  const int tid = threadIdx.x;            // 256
  const int wave = tid >> 6, lane = tid & 63;
  const int s = blockIdx.x * 4 + wave;
  __shared__ float pts[N*3];
  for (int i = tid; i < N*3; i += 256) pts[i] = xyz[b*N*3 + i];
  __syncthreads();
  const float qx = new_xyz[(b*S+s)*3+0], qy = new_xyz[(b*S+s)*3+1], qz = new_xyz[(b*S+s)*3+2];
  const float qn = qx*qx + qy*qy + qz*qz;
  float d[16];
  #pragma unroll
  for (int j = 0; j < 16; ++j) {
    const int p = j*64 + lane;
    const float px = pts[p*3+0], py = pts[p*3+1], pz = pts[p*3+2];
    const float dot = qx*px + qy*py + qz*pz;
    const float pn  = px*px + py*py + pz*pz;
    d[j] = (-2.0f*dot + qn) + pn;          // reference's expanded form + add order
  }
  unsigned mask = 0xFFFFu;
  for (int k = 0; k < K; ++k) {
    float bv = INFINITY; int bj = 0;
    #pragma unroll
    for (int j = 0; j < 16; ++j) {
      if (((mask >> j) & 1u) && d[j] < bv) { bv = d[j]; bj = j; }
    }
    int bp = bj*64 + lane;
    #pragma unroll
    for (int m = 1; m < 64; m <<= 1) {
      const float ov = __shfl_xor(bv, m);
      const int   op = __shfl_xor(bp, m);
      if (ov < bv || (ov == bv && op < bp)) { bv = ov; bp = op; }
    }
    if (lane == 0) knn_idx[(b*S+s)*K + k] = bp;
    if ((bp & 63) == lane) mask &= ~(1u << (bp >> 6));
  }
}

// ---------------- per-(b,s) mean over K + centered partial sums ----------------
__global__ void group_stats_kernel(const float* __restrict__ feats, const float* __restrict__ xyz,
                                   const int* __restrict__ knn_idx, float* __restrict__ mean_out,
                                   float2* __restrict__ partials) {
  const int bs = blockIdx.x;
  const int b = bs / S;
  const int t = threadIdx.x;              // 128
  __shared__ int sidx[K];
  if (t < K) sidx[t] = knn_idx[bs*K + t];
  __syncthreads();
  float v[K];
  float ls = 0.0f, lsq = 0.0f;
  if (t < GC) {
    float sum = 0.0f;
    #pragma unroll
    for (int k = 0; k < K; ++k) {
      const int p = sidx[k];
      const float g = (t < CF) ? feats[(b*N+p)*CF + t] : xyz[(b*N+p)*3 + (t-CF)];
      v[k] = g; sum += g;
    }
    const float mean = sum * (1.0f/K);
    mean_out[bs*GC + t] = mean;
    #pragma unroll
    for (int k = 0; k < K; ++k) {
      const float c = v[k] - mean;
      ls += c; lsq += c*c;
    }
  }
  __shared__ float r1[128], r2[128];
  r1[t] = ls; r2[t] = lsq;
  __syncthreads();
  for (int off = 64; off >= 1; off >>= 1) {
    if (t < off) { r1[t] += r1[t+off]; r2[t] += r2[t+off]; }
    __syncthreads();
  }
  if (t == 0) partials[bs] = make_float2(r1[0], r2[0]);
}

// ---------------- deterministic batch std (ddof=1), 64-lane double butterfly ----------------
__global__ void stats_kernel(const float2* __restrict__ partials, float* __restrict__ invstd) {
  const int b = blockIdx.x;
  const int lane = threadIdx.x;           // 64
  double su = 0.0, sq = 0.0;
  for (int i = lane; i < S; i += 64) {
    const float2 p = partials[b*S+i];
    su += (double)p.x; sq += (double)p.y;
  }
  #pragma unroll
  for (int m = 1; m < 64; m <<= 1) { su += __shfl_xor(su, m); sq += __shfl_xor(sq, m); }
  if (lane == 0) {
    const double nn = (double)S * K * GC;
    const double var = (sq - su*su/nn) / (nn - 1.0);
    invstd[b] = 1.0f / ((float)sqrt(var) + 1e-5f);
  }
}

// ---------------- transfer: normalize+affine, 1x1 conv + BN + ReLU + max over K ----------------
// (r4 config: 128 threads, one output channel per thread.)
__global__ void transfer_kernel(const float* __restrict__ feats, const float* __restrict__ xyz,
                                const int* __restrict__ knn_idx, const int* __restrict__ fps_idx,
                                const float* __restrict__ mean_in, const float* __restrict__ invstd,
                                const float* __restrict__ alpha, const float* __restrict__ beta,
                                const float* __restrict__ W_t, const float* __restrict__ b_t,
                                const float* __restrict__ bn_g, const float* __restrict__ bn_b,
                                float* __restrict__ v_k) {
  const int bs = blockIdx.x;
  const int b = bs / S;
  const int t = threadIdx.x;              // 128
  __shared__ __align__(16) float np_s[K][DPAD];
  __shared__ int sidx[K];
  __shared__ int sanchor;
  if (t < K) sidx[t] = knn_idx[bs*K + t];
  if (t == 0) sanchor = fps_idx[bs];
  __syncthreads();
  const float sinv = invstd[b];
  for (int k = 0; k < K; ++k) {
    const int p = sidx[k];
    for (int c = t; c < DPAD; c += 128) {
      float val = 0.0f;
      if (c < GC) {
        const float g = (c < CF) ? feats[(b*N+p)*CF + c] : xyz[(b*N+p)*3 + (c-CF)];
        val = (g - mean_in[bs*GC + c]) * sinv * alpha[c] + beta[c];
      } else if (c < DIN) {
        val = feats[(b*N+sanchor)*CF + (c - GC)];  // anchor feats, not normalized
      }
      np_s[k][c] = val;
    }
  }
  __syncthreads();
  float acc[K];
  const float bt = b_t[t];
  #pragma unroll
  for (int k = 0; k < K; ++k) acc[k] = bt;
  for (int d4 = 0; d4 < DPAD/4; ++d4) {
    const int d = d4*4;
    const float w0 = W_t[(d+0)*DM + t];
    const float w1 = W_t[(d+1)*DM + t];
    const float w2 = W_t[(d+2)*DM + t];
    const float w3 = (d+3 < DIN) ? W_t[(d+3)*DM + t] : 0.0f;
    #pragma unroll
    for (int k = 0; k < K; ++k) {
      const float4 f = *reinterpret_cast<const float4*>(&np_s[k][d]);
      acc[k] = acc[k] + f.x*w0 + f.y*w1 + f.z*w2 + f.w*w3;
    }
  }
  const float scale = bn_g[t] / sqrtf(1.0f + 1e-5f);
  const float shift = bn_b[t];
  float mx = -INFINITY;
  #pragma unroll
  for (int k = 0; k < K; ++k) {
    const float y = fmaxf(acc[k]*scale + shift, 0.0f);
    mx = fmaxf(mx, y);
  }
  v_k[bs*DM + t] = mx;
}

// ---------------- 3-NN inverse-distance interpolation, one wave per point ----------------
__global__ void interp_kernel(const float* __restrict__ xyz, const float* __restrict__ new_xyz,
                              const float* __restrict__ v_k, float* __restrict__ v_q) {
  const int b = blockIdx.y;
  const int tid = threadIdx.x;            // 256
  const int wave = tid >> 6, lane = tid & 63;
  const int n = blockIdx.x*4 + wave;
  __shared__ float pts[S*3];
  for (int i = tid; i < S*3; i += 256) pts[i] = new_xyz[b*S*3 + i];
  __syncthreads();
  const float qx = xyz[(b*N+n)*3+0], qy = xyz[(b*N+n)*3+1], qz = xyz[(b*N+n)*3+2];
  const float qn = qx*qx + qy*qy + qz*qz;
  float d[8];
  #pragma unroll
  for (int j = 0; j < 8; ++j) {
    const int p = j*64 + lane;
    const float px = pts[p*3+0], py = pts[p*3+1], pz = pts[p*3+2];
    const float dot = qx*px + qy*py + qz*pz;
    const float pn  = px*px + py*py + pz*pz;
    d[j] = (-2.0f*dot + qn) + pn;
  }
  unsigned mask = 0xFFu;
  float sd[3]; int sp[3];
  #pragma unroll
  for (int k = 0; k < 3; ++k) {
    float bv = INFINITY; int bj = 0;
    #pragma unroll
    for (int j = 0; j < 8; ++j) {
      if (((mask >> j) & 1u) && d[j] < bv) { bv = d[j]; bj = j; }
    }
    int bp = bj*64 + lane;
    #pragma unroll
    for (int m = 1; m < 64; m <<= 1) {
      const float ov = __shfl_xor(bv, m);
      const int   op = __shfl_xor(bp, m);
      if (ov < bv || (ov == bv && op < bp)) { bv = ov; bp = op; }
    }
    sd[k] = bv; sp[k] = bp;
    if ((bp & 63) == lane) mask &= ~(1u << (bp >> 6));
  }
  float w0 = 1.0f / fmaxf(sd[0], 1e-10f);
  float w1 = 1.0f / fmaxf(sd[1], 1e-10f);
  float w2 = 1.0f / fmaxf(sd[2], 1e-10f);
  const float wsum = w0 + w1 + w2;
  w0 /= wsum; w1 /= wsum; w2 /= wsum;
  const float* vk0 = v_k + (b*S + sp[0])*DM;
  const float* vk1 = v_k + (b*S + sp[1])*DM;
  const float* vk2 = v_k + (b*S + sp[2])*DM;
  #pragma unroll
  for (int c = lane; c < DM; c += 64) {
    v_q[(b*N+n)*DM + c] = w0*vk0[c] + w1*vk1[c] + w2*vk2[c];
  }
}

// ---------------- fused linears: q rows (B*N) + kv rows (B*S, both k and v) ----------------
__global__ void linear_fused_kernel(const float* __restrict__ vq, const float* __restrict__ vk,
                                    const float* __restrict__ Wq, const float* __restrict__ bq,
                                    const float* __restrict__ Wk, const float* __restrict__ bk,
                                    const float* __restrict__ Wv, const float* __restrict__ bv,
                                    float* __restrict__ qbuf, float* __restrict__ kpb,
                                    float* __restrict__ vpb) {
  const int r = blockIdx.x;               // [0, B*N + B*S)
  const int t = threadIdx.x;              // 128
  __shared__ float rin[DM];
  if (r < B*N) {
    rin[t] = vq[r*DM + t];
    __syncthreads();
    float acc = bq[t];
    for (int d = 0; d < DM; ++d) acc += rin[d] * Wq[d*DM + t];
    qbuf[r*DM + t] = acc;
  } else {
    const int rk = r - B*N;
    rin[t] = vk[rk*DM + t];
    __syncthreads();
    float acck = bk[t], accv = bv[t];
    for (int d = 0; d < DM; ++d) {
      const float f = rin[d];
      acck += f * Wk[d*DM + t];
      accv += f * Wv[d*DM + t];
    }
    kpb[rk*DM + t] = acck;
    vpb[rk*DM + t] = accv;
  }
}

// ---------------- cross-attention (RPE MLP fused, r4 inner) + output projection ----------------
__global__ void attn_kernel(const float* __restrict__ xyz, const float* __restrict__ new_xyz,
                            const float* __restrict__ qb, const float* __restrict__ kp,
                            const float* __restrict__ vp, const float* __restrict__ Wp1,
                            const float* __restrict__ bp1, const float* __restrict__ Wp2,
                            const float* __restrict__ bp2, const float* __restrict__ Wo,
                            const float* __restrict__ bo, float* __restrict__ out) {
  const int bn = blockIdx.x;              // b*N + n
  const int b = bn / N;
  const int t = threadIdx.x;              // 128
  __shared__ __align__(16) float e[NH][EPAD];
  __shared__ float qn_s[DM];
  __shared__ float oa[DM];
  __shared__ float ssum[NH];
  qn_s[t] = qb[bn*DM + t];
  __syncthreads();
  const float qx = xyz[bn*3+0], qy = xyz[bn*3+1], qz = xyz[bn*3+2];
  const float rs = 0.17677669529663687f;  // 1/sqrt(32)
  for (int j = t; j < S; j += 128) {
    const float px = new_xyz[(b*S+j)*3+0], py = new_xyz[(b*S+j)*3+1], pz = new_xyz[(b*S+j)*3+2];
    const float rx = qx-px, ry = qy-py, rz = qz-pz;
    float r0 = bp2[0], r1 = bp2[1], r2 = bp2[2], r3 = bp2[3];
    for (int m = 0; m < DM; ++m) {
      float hm = rx*Wp1[m] + ry*Wp1[DM+m] + rz*Wp1[2*DM+m] + bp1[m];
      hm = fmaxf(hm, 0.0f);
      r0 += hm*Wp2[m*NH+0]; r1 += hm*Wp2[m*NH+1];
      r2 += hm*Wp2[m*NH+2]; r3 += hm*Wp2[m*NH+3];
    }
    const float rpe[NH] = {r0, r1, r2, r3};
    #pragma unroll
    for (int h = 0; h < NH; ++h) {
      const float* kr = kp + (b*S+j)*DM + h*DH;
      const float* qr = qn_s + h*DH;
      float acc = 0.0f;
      #pragma unroll
      for (int dd = 0; dd < DH; ++dd) acc += qr[dd]*kr[dd];
      e[h][j] = acc*rs + rpe[h];
    }
  }
  __syncthreads();
  const int h = t >> 5, g = t & 31;       // 32 threads per head
  float mx = -INFINITY;
  for (int j = g; j < S; j += 32) mx = fmaxf(mx, e[h][j]);
  #pragma unroll
  for (int m = 16; m >= 1; m >>= 1) mx = fmaxf(mx, __shfl_xor(mx, m));
  float sum = 0.0f;
  for (int j = g; j < S; j += 32) { const float ex = expf(e[h][j]-mx); e[h][j] = ex; sum += ex; }
  #pragma unroll
  for (int m = 16; m >= 1; m >>= 1) sum += __shfl_xor(sum, m);
  if (g == 0) ssum[h] = sum;
  __syncthreads();
  float acc = 0.0f;
  for (int j = 0; j < S; j += 4) {
    const float4 ev = *reinterpret_cast<const float4*>(&e[h][j]);
    acc += ev.x * vp[(b*S+j+0)*DM + t];
    acc += ev.y * vp[(b*S+j+1)*DM + t];
    acc += ev.z * vp[(b*S+j+2)*DM + t];
    acc += ev.w * vp[(b*S+j+3)*DM + t];
  }
  oa[t] = acc / ssum[h];
  __syncthreads();
  float facc = bo[t];
  for (int d = 0; d < DM; ++d) facc += oa[d] * Wo[d*DM + t];
  out[bn*DM + t] = facc;
}

}  // namespace

extern "C" void kernel_launch(void* const* d_in, const int* in_sizes, int n_in,
                              void* d_out, int out_size, void* d_ws, size_t ws_size,
                              hipStream_t stream) {
  const float* xyz   = (const float*)d_in[0];
  const float* feats = (const float*)d_in[1];
  const float* alpha = (const float*)d_in[2];
  const float* beta  = (const float*)d_in[3];
  const float* W_t   = (const float*)d_in[4];
  const float* b_t   = (const float*)d_in[5];
  const float* bn_g  = (const float*)d_in[6];
  const float* bn_b  = (const float*)d_in[7];
  const float* Wq = (const float*)d_in[8];  const float* bq = (const float*)d_in[9];
  const float* Wk = (const float*)d_in[10]; const float* bk = (const float*)d_in[11];
  const float* Wv = (const float*)d_in[12]; const float* bv = (const float*)d_in[13];
  const float* Wo = (const float*)d_in[14]; const float* bo = (const float*)d_in[15];
  const float* Wp1= (const float*)d_in[16]; const float* bp1= (const float*)d_in[17];
  const float* Wp2= (const float*)d_in[18]; const float* bp2= (const float*)d_in[19];

  char* w = (char*)d_ws;
  int*    fps_i = (int*)   (w + 0);        // B*S ints            (4 KB)
  float*  nxyz  = (float*) (w + 4096);     // B*S*3               (12 KB)
  int*    knn_i = (int*)   (w + 16384);    // B*S*K ints          (128 KB)
  float*  meanb = (float*) (w + 147456);   // B*S*GC              (268 KB)
  float2* part  = (float2*)(w + 421888);   // B*S float2          (8 KB)
  float*  invs  = (float*) (w + 430080);   // B floats
  float*  vk    = (float*) (w + 430336);   // B*S*DM              (512 KB)
  float*  vq    = (float*) (w + 954624);   // B*N*DM              (1 MB)
  float*  qbuf  = (float*) (w + 2003200);  // B*N*DM              (1 MB)
  float*  kpb   = (float*) (w + 3051776);  // B*S*DM              (512 KB)
  float*  vpb   = (float*) (w + 3576064);  // B*S*DM              (512 KB)
  float*  outf  = (float*)d_out;

  fps_kernel<<<1, 64, 0, stream>>>(xyz, fps_i, nxyz);
  knn_kernel<<<dim3(S/4, B), 256, 0, stream>>>(xyz, nxyz, knn_i);
  group_stats_kernel<<<B*S, 128, 0, stream>>>(feats, xyz, knn_i, meanb, part);
  stats_kernel<<<B, 64, 0, stream>>>(part, invs);
  transfer_kernel<<<B*S, 128, 0, stream>>>(feats, xyz, knn_i, fps_i, meanb, invs,
                                           alpha, beta, W_t, b_t, bn_g, bn_b, vk);
  interp_kernel<<<dim3(N/4, B), 256, 0, stream>>>(xyz, nxyz, vk, vq);
  linear_fused_kernel<<<B*N + B*S, 128, 0, stream>>>(vq, vk, Wq, bq, Wk, bk, Wv, bv,
                                                     qbuf, kpb, vpb);
  attn_kernel<<<B*N, 128, 0, stream>>>(xyz, nxyz, qbuf, kpb, vpb, Wp1, bp1, Wp2, bp2, Wo, bo, outf);
}

// Round 9
// 453.859 us; speedup vs baseline: 1.4113x; 1.4113x over previous
//
#include <hip/hip_runtime.h>
#include <math.h>

namespace {

constexpr int B  = 2;
constexpr int N  = 1024;
constexpr int CF = 64;    // C_FEAT
constexpr int S  = 512;
constexpr int K  = 32;
constexpr int DM = 128;   // D_MODEL
constexpr int NH = 4;
constexpr int DH = 32;
constexpr int GC = 67;    // grouped channels = CF + 3
constexpr int DIN = 131;  // GC + CF
constexpr int DPAD = 132; // padded row for float4 LDS reads
constexpr int EPAD = 516; // S+4: keeps e rows 16B-aligned for float4 reads

typedef float f2 __attribute__((ext_vector_type(2)));

// DPP helpers. Reduce-to-lane63 pattern: row_shr:1/2/4/8, row_bcast:15, row_bcast:31.
template <int CTRL>
__device__ inline float dpp_mov_f(float v) {
  // bound_ctrl=true: invalid lanes read 0 — valid identity for fmax of nonneg values.
  return __int_as_float(__builtin_amdgcn_update_dpp(0, __float_as_int(v), CTRL, 0xF, 0xF, true));
}
template <int CTRL>
__device__ inline unsigned dpp_mov_self_u(unsigned v) {
  // bound_ctrl=false with old=v: invalid lanes yield v — identity for min.
  return (unsigned)__builtin_amdgcn_update_dpp((int)v, (int)v, CTRL, 0xF, 0xF, false);
}

// ---------------- FPS: single wave per batch (grid=B, r7 structure), pk-f32 dist update ----------------
// Each lane owns 16 points; f2 slot j packs points (2j)*64+lane and (2j+1)*64+lane.
// Distance update on float2 ext-vectors -> v_pk_{add,mul,fma}_f32 (double-rate,
// per-element rounding identical to scalar). Reduce = r4's verified two-pass
// (f32 DPP max, then min-index among exact maxima -> jnp.argmax tie semantics).
__global__ void __launch_bounds__(64, 1)
fps_kernel(const float* __restrict__ xyz, int* __restrict__ fps_idx,
           float* __restrict__ new_xyz) {
  const int b = blockIdx.x;
  const int lane = threadIdx.x;           // 64 threads = 1 wave
  __shared__ __align__(16) float4 pts4[N];
  __shared__ int farhist[S];
  for (int p = lane; p < N; p += 64) {
    pts4[p] = make_float4(xyz[b*N*3 + p*3+0], xyz[b*N*3 + p*3+1], xyz[b*N*3 + p*3+2], 0.0f);
  }
  __syncthreads();
  f2 X[8], Y[8], Z[8];
  float dist[16];
  #pragma unroll
  for (int j = 0; j < 8; ++j) {
    const float4 a = pts4[(2*j)*64 + lane];
    const float4 c = pts4[(2*j+1)*64 + lane];
    X[j] = f2{a.x, c.x}; Y[j] = f2{a.y, c.y}; Z[j] = f2{a.z, c.z};
  }
  #pragma unroll
  for (int k = 0; k < 16; ++k) dist[k] = 1e10f;
  int far = 0;
  for (int s = 0; s < S; ++s) {
    if (lane == 0) farhist[s] = far;
    const float4 c = pts4[far];
    const f2 cx = f2{c.x, c.x}, cy = f2{c.y, c.y}, cz = f2{c.z, c.z};
    #pragma unroll
    for (int j = 0; j < 8; ++j) {
      const f2 dx = X[j] - cx, dy = Y[j] - cy, dz = Z[j] - cz;
      const f2 q = dx*dx + dy*dy + dz*dz;    // same per-element expression as reference
      dist[2*j]   = fminf(dist[2*j],   q.x);
      dist[2*j+1] = fminf(dist[2*j+1], q.y);
    }
    // pass 1: lane-local max (tree)
    float m[8];
    #pragma unroll
    for (int j = 0; j < 8; ++j) m[j] = fmaxf(dist[j], dist[j+8]);
    #pragma unroll
    for (int j = 0; j < 4; ++j) m[j] = fmaxf(m[j], m[j+4]);
    float mv = fmaxf(fmaxf(m[0], m[2]), fmaxf(m[1], m[3]));
    // wave64 max via DPP, result valid in lane 63
    mv = fmaxf(mv, dpp_mov_f<0x111>(mv));
    mv = fmaxf(mv, dpp_mov_f<0x112>(mv));
    mv = fmaxf(mv, dpp_mov_f<0x114>(mv));
    mv = fmaxf(mv, dpp_mov_f<0x118>(mv));
    mv = fmaxf(mv, dpp_mov_f<0x142>(mv));
    mv = fmaxf(mv, dpp_mov_f<0x143>(mv));
    const float maxv = __int_as_float(__builtin_amdgcn_readlane(__float_as_int(mv), 63));
    // pass 2: min index among exact maxima
    unsigned cnd[16];
    #pragma unroll
    for (int k = 0; k < 16; ++k) {
      cnd[k] = (dist[k] == maxv) ? (unsigned)(k*64 + lane) : 0xFFFFFFFFu;
    }
    #pragma unroll
    for (int k = 0; k < 8; ++k) cnd[k] = min(cnd[k], cnd[k+8]);
    #pragma unroll
    for (int k = 0; k < 4; ++k) cnd[k] = min(cnd[k], cnd[k+4]);
    unsigned cand = min(min(cnd[0], cnd[2]), min(cnd[1], cnd[3]));
    cand = min(cand, dpp_mov_self_u<0x111>(cand));
    cand = min(cand, dpp_mov_self_u<0x112>(cand));
    cand = min(cand, dpp_mov_self_u<0x114>(cand));
    cand = min(cand, dpp_mov_self_u<0x118>(cand));
    cand = min(cand, dpp_mov_self_u<0x142>(cand));
    cand = min(cand, dpp_mov_self_u<0x143>(cand));
    far = __builtin_amdgcn_readlane((int)cand, 63);
  }
  __syncthreads();
  // epilogue: write fps_idx and new_xyz from history
  for (int s = lane; s < S; s += 64) {
    const int f = farhist[s];
    const float4 c = pts4[f];
    fps_idx[b*S+s] = f;
    new_xyz[(b*S+s)*3+0] = c.x;
    new_xyz[(b*S+s)*3+1] = c.y;
    new_xyz[(b*S+s)*3+2] = c.z;
  }
}

// ---------------- KNN (K=32 of N=1024), one wave per query ----------------
__global__ void knn_kernel(const float* __restrict__ xyz, const float* __restrict__ new_xyz,
                           int* __restrict__ knn_idx) {
  const int b = blockIdx.y;
  const int tid = threadIdx.x;            // 256
  const int wave = tid >> 6, lane = tid & 63;
  const int s = blockIdx.x * 4 + wave;
  __shared__ float pts[N*3];
  for (int i = tid; i < N*3; i += 256) pts[i] = xyz[b*N*3 + i];
  __syncthreads();
  const float qx = new_xyz[(b*S+s)*3+0], qy = new_xyz[(b*S+s)*3+1], qz = new_xyz[(b*S+s)*3+2];
  const float qn = qx*qx + qy*qy + qz*qz;
  float d[16];
  #pragma unroll
  for (int j = 0; j < 16; ++j) {
    const int p = j*64 + lane;
    const float px = pts[p*3+0], py = pts[p*3+1], pz = pts[p*3+2];
    const float dot = qx*px + qy*py + qz*pz;
    const float pn  = px*px + py*py + pz*pz;
    d[j] = (-2.0f*dot + qn) + pn;          // reference's expanded form + add order
  }
  unsigned mask = 0xFFFFu;
  for (int k = 0; k < K; ++k) {
    float bv = INFINITY; int bj = 0;
    #pragma unroll
    for (int j = 0; j < 16; ++j) {
      if (((mask >> j) & 1u) && d[j] < bv) { bv = d[j]; bj = j; }
    }
    int bp = bj*64 + lane;
    #pragma unroll
    for (int m = 1; m < 64; m <<= 1) {
      const float ov = __shfl_xor(bv, m);
      const int   op = __shfl_xor(bp, m);
      if (ov < bv || (ov == bv && op < bp)) { bv = ov; bp = op; }
    }
    if (lane == 0) knn_idx[(b*S+s)*K + k] = bp;
    if ((bp & 63) == lane) mask &= ~(1u << (bp >> 6));
  }
}

// ---------------- per-(b,s) mean over K + centered partial sums ----------------
__global__ void group_stats_kernel(const float* __restrict__ feats, const float* __restrict__ xyz,
                                   const int* __restrict__ knn_idx, float* __restrict__ mean_out,
                                   float2* __restrict__ partials) {
  const int bs = blockIdx.x;
  const int b = bs / S;
  const int t = threadIdx.x;              // 128
  __shared__ int sidx[K];
  if (t < K) sidx[t] = knn_idx[bs*K + t];
  __syncthreads();
  float v[K];
  float ls = 0.0f, lsq = 0.0f;
  if (t < GC) {
    float sum = 0.0f;
    #pragma unroll
    for (int k = 0; k < K; ++k) {
      const int p = sidx[k];
      const float g = (t < CF) ? feats[(b*N+p)*CF + t] : xyz[(b*N+p)*3 + (t-CF)];
      v[k] = g; sum += g;
    }
    const float mean = sum * (1.0f/K);
    mean_out[bs*GC + t] = mean;
    #pragma unroll
    for (int k = 0; k < K; ++k) {
      const float c = v[k] - mean;
      ls += c; lsq += c*c;
    }
  }
  __shared__ float r1[128], r2[128];
  r1[t] = ls; r2[t] = lsq;
  __syncthreads();
  for (int off = 64; off >= 1; off >>= 1) {
    if (t < off) { r1[t] += r1[t+off]; r2[t] += r2[t+off]; }
    __syncthreads();
  }
  if (t == 0) partials[bs] = make_float2(r1[0], r2[0]);
}

// ---------------- deterministic batch std (ddof=1), 64-lane double butterfly ----------------
__global__ void stats_kernel(const float2* __restrict__ partials, float* __restrict__ invstd) {
  const int b = blockIdx.x;
  const int lane = threadIdx.x;           // 64
  double su = 0.0, sq = 0.0;
  for (int i = lane; i < S; i += 64) {
    const float2 p = partials[b*S+i];
    su += (double)p.x; sq += (double)p.y;
  }
  #pragma unroll
  for (int m = 1; m < 64; m <<= 1) { su += __shfl_xor(su, m); sq += __shfl_xor(sq, m); }
  if (lane == 0) {
    const double nn = (double)S * K * GC;
    const double var = (sq - su*su/nn) / (nn - 1.0);
    invstd[b] = 1.0f / ((float)sqrt(var) + 1e-5f);
  }
}

// ---------------- transfer: normalize+affine, 1x1 conv + BN + ReLU + max over K ----------------
// (r4 config: 128 threads, one output channel per thread.)
__global__ void transfer_kernel(const float* __restrict__ feats, const float* __restrict__ xyz,
                                const int* __restrict__ knn_idx, const int* __restrict__ fps_idx,
                                const float* __restrict__ mean_in, const float* __restrict__ invstd,
                                const float* __restrict__ alpha, const float* __restrict__ beta,
                                const float* __restrict__ W_t, const float* __restrict__ b_t,
                                const float* __restrict__ bn_g, const float* __restrict__ bn_b,
                                float* __restrict__ v_k) {
  const int bs = blockIdx.x;
  const int b = bs / S;
  const int t = threadIdx.x;              // 128
  __shared__ __align__(16) float np_s[K][DPAD];
  __shared__ int sidx[K];
  __shared__ int sanchor;
  if (t < K) sidx[t] = knn_idx[bs*K + t];
  if (t == 0) sanchor = fps_idx[bs];
  __syncthreads();
  const float sinv = invstd[b];
  for (int k = 0; k < K; ++k) {
    const int p = sidx[k];
    for (int c = t; c < DPAD; c += 128) {
      float val = 0.0f;
      if (c < GC) {
        const float g = (c < CF) ? feats[(b*N+p)*CF + c] : xyz[(b*N+p)*3 + (c-CF)];
        val = (g - mean_in[bs*GC + c]) * sinv * alpha[c] + beta[c];
      } else if (c < DIN) {
        val = feats[(b*N+sanchor)*CF + (c - GC)];  // anchor feats, not normalized
      }
      np_s[k][c] = val;
    }
  }
  __syncthreads();
  float acc[K];
  const float bt = b_t[t];
  #pragma unroll
  for (int k = 0; k < K; ++k) acc[k] = bt;
  for (int d4 = 0; d4 < DPAD/4; ++d4) {
    const int d = d4*4;
    const float w0 = W_t[(d+0)*DM + t];
    const float w1 = W_t[(d+1)*DM + t];
    const float w2 = W_t[(d+2)*DM + t];
    const float w3 = (d+3 < DIN) ? W_t[(d+3)*DM + t] : 0.0f;
    #pragma unroll
    for (int k = 0; k < K; ++k) {
      const float4 f = *reinterpret_cast<const float4*>(&np_s[k][d]);
      acc[k] = acc[k] + f.x*w0 + f.y*w1 + f.z*w2 + f.w*w3;
    }
  }
  const float scale = bn_g[t] / sqrtf(1.0f + 1e-5f);
  const float shift = bn_b[t];
  float mx = -INFINITY;
  #pragma unroll
  for (int k = 0; k < K; ++k) {
    const float y = fmaxf(acc[k]*scale + shift, 0.0f);
    mx = fmaxf(mx, y);
  }
  v_k[bs*DM + t] = mx;
}

// ---------------- 3-NN inverse-distance interpolation, one wave per point ----------------
__global__ void interp_kernel(const float* __restrict__ xyz, const float* __restrict__ new_xyz,
                              const float* __restrict__ v_k, float* __restrict__ v_q) {
  const int b = blockIdx.y;
  const int tid = threadIdx.x;            // 256
  const int wave = tid >> 6, lane = tid & 63;
  const int n = blockIdx.x*4 + wave;
  __shared__ float pts[S*3];
  for (int i = tid; i < S*3; i += 256) pts[i] = new_xyz[b*S*3 + i];
  __syncthreads();
  const float qx = xyz[(b*N+n)*3+0], qy = xyz[(b*N+n)*3+1], qz = xyz[(b*N+n)*3+2];
  const float qn = qx*qx + qy*qy + qz*qz;
  float d[8];
  #pragma unroll
  for (int j = 0; j < 8; ++j) {
    const int p = j*64 + lane;
    const float px = pts[p*3+0], py = pts[p*3+1], pz = pts[p*3+2];
    const float dot = qx*px + qy*py + qz*pz;
    const float pn  = px*px + py*py + pz*pz;
    d[j] = (-2.0f*dot + qn) + pn;
  }
  unsigned mask = 0xFFu;
  float sd[3]; int sp[3];
  #pragma unroll
  for (int k = 0; k < 3; ++k) {
    float bv = INFINITY; int bj = 0;
    #pragma unroll
    for (int j = 0; j < 8; ++j) {
      if (((mask >> j) & 1u) && d[j] < bv) { bv = d[j]; bj = j; }
    }
    int bp = bj*64 + lane;
    #pragma unroll
    for (int m = 1; m < 64; m <<= 1) {
      const float ov = __shfl_xor(bv, m);
      const int   op = __shfl_xor(bp, m);
      if (ov < bv || (ov == bv && op < bp)) { bv = ov; bp = op; }
    }
    sd[k] = bv; sp[k] = bp;
    if ((bp & 63) == lane) mask &= ~(1u << (bp >> 6));
  }
  float w0 = 1.0f / fmaxf(sd[0], 1e-10f);
  float w1 = 1.0f / fmaxf(sd[1], 1e-10f);
  float w2 = 1.0f / fmaxf(sd[2], 1e-10f);
  const float wsum = w0 + w1 + w2;
  w0 /= wsum; w1 /= wsum; w2 /= wsum;
  const float* vk0 = v_k + (b*S + sp[0])*DM;
  const float* vk1 = v_k + (b*S + sp[1])*DM;
  const float* vk2 = v_k + (b*S + sp[2])*DM;
  #pragma unroll
  for (int c = lane; c < DM; c += 64) {
    v_q[(b*N+n)*DM + c] = w0*vk0[c] + w1*vk1[c] + w2*vk2[c];
  }
}

// ---------------- fused linears: q rows (B*N) + kv rows (B*S, both k and v) ----------------
__global__ void linear_fused_kernel(const float* __restrict__ vq, const float* __restrict__ vk,
                                    const float* __restrict__ Wq, const float* __restrict__ bq,
                                    const float* __restrict__ Wk, const float* __restrict__ bk,
                                    const float* __restrict__ Wv, const float* __restrict__ bv,
                                    float* __restrict__ qbuf, float* __restrict__ kpb,
                                    float* __restrict__ vpb) {
  const int r = blockIdx.x;               // [0, B*N + B*S)
  const int t = threadIdx.x;              // 128
  __shared__ float rin[DM];
  if (r < B*N) {
    rin[t] = vq[r*DM + t];
    __syncthreads();
    float acc = bq[t];
    for (int d = 0; d < DM; ++d) acc += rin[d] * Wq[d*DM + t];
    qbuf[r*DM + t] = acc;
  } else {
    const int rk = r - B*N;
    rin[t] = vk[rk*DM + t];
    __syncthreads();
    float acck = bk[t], accv = bv[t];
    for (int d = 0; d < DM; ++d) {
      const float f = rin[d];
      acck += f * Wk[d*DM + t];
      accv += f * Wv[d*DM + t];
    }
    kpb[rk*DM + t] = acck;
    vpb[rk*DM + t] = accv;
  }
}

// ---------------- cross-attention (RPE MLP fused, r4 inner) + output projection ----------------
__global__ void attn_kernel(const float* __restrict__ xyz, const float* __restrict__ new_xyz,
                            const float* __restrict__ qb, const float* __restrict__ kp,
                            const float* __restrict__ vp, const float* __restrict__ Wp1,
                            const float* __restrict__ bp1, const float* __restrict__ Wp2,
                            const float* __restrict__ bp2, const float* __restrict__ Wo,
                            const float* __restrict__ bo, float* __restrict__ out) {
  const int bn = blockIdx.x;              // b*N + n
  const int b = bn / N;
  const int t = threadIdx.x;              // 128
  __shared__ __align__(16) float e[NH][EPAD];
  __shared__ float qn_s[DM];
  __shared__ float oa[DM];
  __shared__ float ssum[NH];
  qn_s[t] = qb[bn*DM + t];
  __syncthreads();
  const float qx = xyz[bn*3+0], qy = xyz[bn*3+1], qz = xyz[bn*3+2];
  const float rs = 0.17677669529663687f;  // 1/sqrt(32)
  for (int j = t; j < S; j += 128) {
    const float px = new_xyz[(b*S+j)*3+0], py = new_xyz[(b*S+j)*3+1], pz = new_xyz[(b*S+j)*3+2];
    const float rx = qx-px, ry = qy-py, rz = qz-pz;
    float r0 = bp2[0], r1 = bp2[1], r2 = bp2[2], r3 = bp2[3];
    for (int m = 0; m < DM; ++m) {
      float hm = rx*Wp1[m] + ry*Wp1[DM+m] + rz*Wp1[2*DM+m] + bp1[m];
      hm = fmaxf(hm, 0.0f);
      r0 += hm*Wp2[m*NH+0]; r1 += hm*Wp2[m*NH+1];
      r2 += hm*Wp2[m*NH+2]; r3 += hm*Wp2[m*NH+3];
    }
    const float rpe[NH] = {r0, r1, r2, r3};
    #pragma unroll
    for (int h = 0; h < NH; ++h) {
      const float* kr = kp + (b*S+j)*DM + h*DH;
      const float* qr = qn_s + h*DH;
      float acc = 0.0f;
      #pragma unroll
      for (int dd = 0; dd < DH; ++dd) acc += qr[dd]*kr[dd];
      e[h][j] = acc*rs + rpe[h];
    }
  }
  __syncthreads();
  const int h = t >> 5, g = t & 31;       // 32 threads per head
  float mx = -INFINITY;
  for (int j = g; j < S; j += 32) mx = fmaxf(mx, e[h][j]);
  #pragma unroll
  for (int m = 16; m >= 1; m >>= 1) mx = fmaxf(mx, __shfl_xor(mx, m));
  float sum = 0.0f;
  for (int j = g; j < S; j += 32) { const float ex = expf(e[h][j]-mx); e[h][j] = ex; sum += ex; }
  #pragma unroll
  for (int m = 16; m >= 1; m >>= 1) sum += __shfl_xor(sum, m);
  if (g == 0) ssum[h] = sum;
  __syncthreads();
  float acc = 0.0f;
  for (int j = 0; j < S; j += 4) {
    const float4 ev = *reinterpret_cast<const float4*>(&e[h][j]);
    acc += ev.x * vp[(b*S+j+0)*DM + t];
    acc += ev.y * vp[(b*S+j+1)*DM + t];
    acc += ev.z * vp[(b*S+j+2)*DM + t];
    acc += ev.w * vp[(b*S+j+3)*DM + t];
  }
  oa[t] = acc / ssum[h];
  __syncthreads();
  float facc = bo[t];
  for (int d = 0; d < DM; ++d) facc += oa[d] * Wo[d*DM + t];
  out[bn*DM + t] = facc;
}

}  // namespace

extern "C" void kernel_launch(void* const* d_in, const int* in_sizes, int n_in,
                              void* d_out, int out_size, void* d_ws, size_t ws_size,
                              hipStream_t stream) {
  const float* xyz   = (const float*)d_in[0];
  const float* feats = (const float*)d_in[1];
  const float* alpha = (const float*)d_in[2];
  const float* beta  = (const float*)d_in[3];
  const float* W_t   = (const float*)d_in[4];
  const float* b_t   = (const float*)d_in[5];
  const float* bn_g  = (const float*)d_in[6];
  const float* bn_b  = (const float*)d_in[7];
  const float* Wq = (const float*)d_in[8];  const float* bq = (const float*)d_in[9];
  const float* Wk = (const float*)d_in[10]; const float* bk = (const float*)d_in[11];
  const float* Wv = (const float*)d_in[12]; const float* bv = (const float*)d_in[13];
  const float* Wo = (const float*)d_in[14]; const float* bo = (const float*)d_in[15];
  const float* Wp1= (const float*)d_in[16]; const float* bp1= (const float*)d_in[17];
  const float* Wp2= (const float*)d_in[18]; const float* bp2= (const float*)d_in[19];

  char* w = (char*)d_ws;
  int*    fps_i = (int*)   (w + 0);        // B*S ints            (4 KB)
  float*  nxyz  = (float*) (w + 4096);     // B*S*3               (12 KB)
  int*    knn_i = (int*)   (w + 16384);    // B*S*K ints          (128 KB)
  float*  meanb = (float*) (w + 147456);   // B*S*GC              (268 KB)
  float2* part  = (float2*)(w + 421888);   // B*S float2          (8 KB)
  float*  invs  = (float*) (w + 430080);   // B floats
  float*  vk    = (float*) (w + 430336);   // B*S*DM              (512 KB)
  float*  vq    = (float*) (w + 954624);   // B*N*DM              (1 MB)
  float*  qbuf  = (float*) (w + 2003200);  // B*N*DM              (1 MB)
  float*  kpb   = (float*) (w + 3051776);  // B*S*DM              (512 KB)
  float*  vpb   = (float*) (w + 3576064);  // B*S*DM              (512 KB)
  float*  outf  = (float*)d_out;

  fps_kernel<<<B, 64, 0, stream>>>(xyz, fps_i, nxyz);
  knn_kernel<<<dim3(S/4, B), 256, 0, stream>>>(xyz, nxyz, knn_i);
  group_stats_kernel<<<B*S, 128, 0, stream>>>(feats, xyz, knn_i, meanb, part);
  stats_kernel<<<B, 64, 0, stream>>>(part, invs);
  transfer_kernel<<<B*S, 128, 0, stream>>>(feats, xyz, knn_i, fps_i, meanb, invs,
                                           alpha, beta, W_t, b_t, bn_g, bn_b, vk);
  interp_kernel<<<dim3(N/4, B), 256, 0, stream>>>(xyz, nxyz, vk, vq);
  linear_fused_kernel<<<B*N + B*S, 128, 0, stream>>>(vq, vk, Wq, bq, Wk, bk, Wv, bv,
                                                     qbuf, kpb, vpb);
  attn_kernel<<<B*N, 128, 0, stream>>>(xyz, nxyz, qbuf, kpb, vpb, Wp1, bp1, Wp2, bp2, Wo, bo, outf);
}

// Round 10
// 452.742 us; speedup vs baseline: 1.4147x; 1.0025x over previous
//
#include <hip/hip_runtime.h>
#include <math.h>

namespace {

constexpr int B  = 2;
constexpr int N  = 1024;
constexpr int CF = 64;    // C_FEAT
constexpr int S  = 512;
constexpr int K  = 32;
constexpr int DM = 128;   // D_MODEL
constexpr int NH = 4;
constexpr int DH = 32;
constexpr int GC = 67;    // grouped channels = CF + 3
constexpr int DIN = 131;  // GC + CF
constexpr int DPAD = 132; // padded row for float4 LDS reads
constexpr int EPAD = 516; // S+4: keeps e rows 16B-aligned for float4 reads

typedef float f2 __attribute__((ext_vector_type(2)));

__device__ inline float max3f(float a, float b, float c) { return fmaxf(fmaxf(a, b), c); }
__device__ inline unsigned min3u(unsigned a, unsigned b, unsigned c) { return min(min(a, b), c); }

// DPP helpers. Reduce-to-lane63 pattern: row_shr:1/2/4/8, row_bcast:15, row_bcast:31.
template <int CTRL>
__device__ inline float dpp_mov_f(float v) {
  // bound_ctrl=true: invalid lanes read 0 — valid identity for fmax of nonneg values.
  return __int_as_float(__builtin_amdgcn_update_dpp(0, __float_as_int(v), CTRL, 0xF, 0xF, true));
}
template <int CTRL>
__device__ inline unsigned dpp_mov_self_u(unsigned v) {
  // bound_ctrl=false with old=v: invalid lanes yield v — identity for min.
  return (unsigned)__builtin_amdgcn_update_dpp((int)v, (int)v, CTRL, 0xF, 0xF, false);
}

// ---------------- FPS: single wave per batch, pk-f32 dist update, max3/min3 trees ----------------
// Each lane owns 16 points; f2 slot j packs points (2j)*64+lane and (2j+1)*64+lane.
// Pass 1: f32 max of min-dists (max3 tree + DPP). Pass 2: min index among
// exact-equal maxima (min3 tree + DPP) -> jnp.argmax first-occurrence ties.
__global__ void __launch_bounds__(64, 1)
fps_kernel(const float* __restrict__ xyz, int* __restrict__ fps_idx,
           float* __restrict__ new_xyz) {
  const int b = blockIdx.x;
  const int lane = threadIdx.x;           // 64 threads = 1 wave
  __shared__ __align__(16) float4 pts4[N];
  __shared__ int farhist[S];
  for (int p = lane; p < N; p += 64) {
    pts4[p] = make_float4(xyz[b*N*3 + p*3+0], xyz[b*N*3 + p*3+1], xyz[b*N*3 + p*3+2], 0.0f);
  }
  __syncthreads();
  f2 X[8], Y[8], Z[8];
  float dist[16];
  #pragma unroll
  for (int j = 0; j < 8; ++j) {
    const float4 a = pts4[(2*j)*64 + lane];
    const float4 c = pts4[(2*j+1)*64 + lane];
    X[j] = f2{a.x, c.x}; Y[j] = f2{a.y, c.y}; Z[j] = f2{a.z, c.z};
  }
  #pragma unroll
  for (int k = 0; k < 16; ++k) dist[k] = 1e10f;
  int far = 0;
  for (int s = 0; s < S; ++s) {
    if (lane == 0) farhist[s] = far;
    const float4 c = pts4[far];
    const f2 cx = f2{c.x, c.x}, cy = f2{c.y, c.y}, cz = f2{c.z, c.z};
    #pragma unroll
    for (int j = 0; j < 8; ++j) {
      const f2 dx = X[j] - cx, dy = Y[j] - cy, dz = Z[j] - cz;
      const f2 q = dx*dx + dy*dy + dz*dz;    // same per-element expression as reference
      dist[2*j]   = fminf(dist[2*j],   q.x);
      dist[2*j+1] = fminf(dist[2*j+1], q.y);
    }
    // pass 1: lane-local max via max3 tree (7 ops, depth 3)
    const float l0 = max3f(dist[0],  dist[1],  dist[2]);
    const float l1 = max3f(dist[3],  dist[4],  dist[5]);
    const float l2 = max3f(dist[6],  dist[7],  dist[8]);
    const float l3 = max3f(dist[9],  dist[10], dist[11]);
    const float l4 = max3f(dist[12], dist[13], dist[14]);
    float mv = fmaxf(max3f(l0, l1, l2), max3f(l3, l4, dist[15]));
    // wave64 max via DPP, result valid in lane 63
    mv = fmaxf(mv, dpp_mov_f<0x111>(mv));
    mv = fmaxf(mv, dpp_mov_f<0x112>(mv));
    mv = fmaxf(mv, dpp_mov_f<0x114>(mv));
    mv = fmaxf(mv, dpp_mov_f<0x118>(mv));
    mv = fmaxf(mv, dpp_mov_f<0x142>(mv));
    mv = fmaxf(mv, dpp_mov_f<0x143>(mv));
    const float maxv = __int_as_float(__builtin_amdgcn_readlane(__float_as_int(mv), 63));
    // pass 2: min index among exact maxima (min3 tree)
    unsigned cnd[16];
    #pragma unroll
    for (int k = 0; k < 16; ++k) {
      cnd[k] = (dist[k] == maxv) ? (unsigned)(k*64 + lane) : 0xFFFFFFFFu;
    }
    const unsigned u0 = min3u(cnd[0],  cnd[1],  cnd[2]);
    const unsigned u1 = min3u(cnd[3],  cnd[4],  cnd[5]);
    const unsigned u2 = min3u(cnd[6],  cnd[7],  cnd[8]);
    const unsigned u3 = min3u(cnd[9],  cnd[10], cnd[11]);
    const unsigned u4 = min3u(cnd[12], cnd[13], cnd[14]);
    unsigned cand = min(min3u(u0, u1, u2), min3u(u3, u4, cnd[15]));
    cand = min(cand, dpp_mov_self_u<0x111>(cand));
    cand = min(cand, dpp_mov_self_u<0x112>(cand));
    cand = min(cand, dpp_mov_self_u<0x114>(cand));
    cand = min(cand, dpp_mov_self_u<0x118>(cand));
    cand = min(cand, dpp_mov_self_u<0x142>(cand));
    cand = min(cand, dpp_mov_self_u<0x143>(cand));
    far = __builtin_amdgcn_readlane((int)cand, 63);
  }
  __syncthreads();
  // epilogue: write fps_idx and new_xyz from history
  for (int s = lane; s < S; s += 64) {
    const int f = farhist[s];
    const float4 c = pts4[f];
    fps_idx[b*S+s] = f;
    new_xyz[(b*S+s)*3+0] = c.x;
    new_xyz[(b*S+s)*3+1] = c.y;
    new_xyz[(b*S+s)*3+2] = c.z;
  }
}

// ---------------- KNN (K=32 of N=1024), one wave per query ----------------
__global__ void knn_kernel(const float* __restrict__ xyz, const float* __restrict__ new_xyz,
                           int* __restrict__ knn_idx) {
  const int b = blockIdx.y;
  const int tid = threadIdx.x;            // 256
  const int wave = tid >> 6, lane = tid & 63;
  const int s = blockIdx.x * 4 + wave;
  __shared__ float pts[N*3];
  for (int i = tid; i < N*3; i += 256) pts[i] = xyz[b*N*3 + i];
  __syncthreads();
  const float qx = new_xyz[(b*S+s)*3+0], qy = new_xyz[(b*S+s)*3+1], qz = new_xyz[(b*S+s)*3+2];
  const float qn = qx*qx + qy*qy + qz*qz;
  float d[16];
  #pragma unroll
  for (int j = 0; j < 16; ++j) {
    const int p = j*64 + lane;
    const float px = pts[p*3+0], py = pts[p*3+1], pz = pts[p*3+2];
    const float dot = qx*px + qy*py + qz*pz;
    const float pn  = px*px + py*py + pz*pz;
    d[j] = (-2.0f*dot + qn) + pn;          // reference's expanded form + add order
  }
  unsigned mask = 0xFFFFu;
  for (int k = 0; k < K; ++k) {
    float bv = INFINITY; int bj = 0;
    #pragma unroll
    for (int j = 0; j < 16; ++j) {
      if (((mask >> j) & 1u) && d[j] < bv) { bv = d[j]; bj = j; }
    }
    int bp = bj*64 + lane;
    #pragma unroll
    for (int m = 1; m < 64; m <<= 1) {
      const float ov = __shfl_xor(bv, m);
      const int   op = __shfl_xor(bp, m);
      if (ov < bv || (ov == bv && op < bp)) { bv = ov; bp = op; }
    }
    if (lane == 0) knn_idx[(b*S+s)*K + k] = bp;
    if ((bp & 63) == lane) mask &= ~(1u << (bp >> 6));
  }
}

// ---------------- per-(b,s) mean over K + centered partial sums ----------------
__global__ void group_stats_kernel(const float* __restrict__ feats, const float* __restrict__ xyz,
                                   const int* __restrict__ knn_idx, float* __restrict__ mean_out,
                                   float2* __restrict__ partials) {
  const int bs = blockIdx.x;
  const int b = bs / S;
  const int t = threadIdx.x;              // 128
  __shared__ int sidx[K];
  if (t < K) sidx[t] = knn_idx[bs*K + t];
  __syncthreads();
  float v[K];
  float ls = 0.0f, lsq = 0.0f;
  if (t < GC) {
    float sum = 0.0f;
    #pragma unroll
    for (int k = 0; k < K; ++k) {
      const int p = sidx[k];
      const float g = (t < CF) ? feats[(b*N+p)*CF + t] : xyz[(b*N+p)*3 + (t-CF)];
      v[k] = g; sum += g;
    }
    const float mean = sum * (1.0f/K);
    mean_out[bs*GC + t] = mean;
    #pragma unroll
    for (int k = 0; k < K; ++k) {
      const float c = v[k] - mean;
      ls += c; lsq += c*c;
    }
  }
  __shared__ float r1[128], r2[128];
  r1[t] = ls; r2[t] = lsq;
  __syncthreads();
  for (int off = 64; off >= 1; off >>= 1) {
    if (t < off) { r1[t] += r1[t+off]; r2[t] += r2[t+off]; }
    __syncthreads();
  }
  if (t == 0) partials[bs] = make_float2(r1[0], r2[0]);
}

// ---------------- deterministic batch std (ddof=1), 64-lane double butterfly ----------------
__global__ void stats_kernel(const float2* __restrict__ partials, float* __restrict__ invstd) {
  const int b = blockIdx.x;
  const int lane = threadIdx.x;           // 64
  double su = 0.0, sq = 0.0;
  for (int i = lane; i < S; i += 64) {
    const float2 p = partials[b*S+i];
    su += (double)p.x; sq += (double)p.y;
  }
  #pragma unroll
  for (int m = 1; m < 64; m <<= 1) { su += __shfl_xor(su, m); sq += __shfl_xor(sq, m); }
  if (lane == 0) {
    const double nn = (double)S * K * GC;
    const double var = (sq - su*su/nn) / (nn - 1.0);
    invstd[b] = 1.0f / ((float)sqrt(var) + 1e-5f);
  }
}

// ---------------- transfer: normalize+affine, 1x1 conv + BN + ReLU + max over K
//                  + fused k/v projections of the produced row ----------------
__global__ void transfer_kernel(const float* __restrict__ feats, const float* __restrict__ xyz,
                                const int* __restrict__ knn_idx, const int* __restrict__ fps_idx,
                                const float* __restrict__ mean_in, const float* __restrict__ invstd,
                                const float* __restrict__ alpha, const float* __restrict__ beta,
                                const float* __restrict__ W_t, const float* __restrict__ b_t,
                                const float* __restrict__ bn_g, const float* __restrict__ bn_b,
                                const float* __restrict__ Wk, const float* __restrict__ bk,
                                const float* __restrict__ Wv, const float* __restrict__ bv,
                                float* __restrict__ v_k, float* __restrict__ kpb,
                                float* __restrict__ vpb) {
  const int bs = blockIdx.x;
  const int b = bs / S;
  const int t = threadIdx.x;              // 128
  __shared__ __align__(16) float np_s[K][DPAD];
  __shared__ float vrow[DM];
  __shared__ int sidx[K];
  __shared__ int sanchor;
  if (t < K) sidx[t] = knn_idx[bs*K + t];
  if (t == 0) sanchor = fps_idx[bs];
  __syncthreads();
  const float sinv = invstd[b];
  for (int k = 0; k < K; ++k) {
    const int p = sidx[k];
    for (int c = t; c < DPAD; c += 128) {
      float val = 0.0f;
      if (c < GC) {
        const float g = (c < CF) ? feats[(b*N+p)*CF + c] : xyz[(b*N+p)*3 + (c-CF)];
        val = (g - mean_in[bs*GC + c]) * sinv * alpha[c] + beta[c];
      } else if (c < DIN) {
        val = feats[(b*N+sanchor)*CF + (c - GC)];  // anchor feats, not normalized
      }
      np_s[k][c] = val;
    }
  }
  __syncthreads();
  float acc[K];
  const float bt = b_t[t];
  #pragma unroll
  for (int k = 0; k < K; ++k) acc[k] = bt;
  for (int d4 = 0; d4 < DPAD/4; ++d4) {
    const int d = d4*4;
    const float w0 = W_t[(d+0)*DM + t];
    const float w1 = W_t[(d+1)*DM + t];
    const float w2 = W_t[(d+2)*DM + t];
    const float w3 = (d+3 < DIN) ? W_t[(d+3)*DM + t] : 0.0f;
    #pragma unroll
    for (int k = 0; k < K; ++k) {
      const float4 f = *reinterpret_cast<const float4*>(&np_s[k][d]);
      acc[k] = acc[k] + f.x*w0 + f.y*w1 + f.z*w2 + f.w*w3;
    }
  }
  const float scale = bn_g[t] / sqrtf(1.0f + 1e-5f);
  const float shift = bn_b[t];
  float mx = -INFINITY;
  #pragma unroll
  for (int k = 0; k < K; ++k) {
    const float y = fmaxf(acc[k]*scale + shift, 0.0f);
    mx = fmaxf(mx, y);
  }
  v_k[bs*DM + t] = mx;
  vrow[t] = mx;
  __syncthreads();
  // fused k/v projections: same per-channel serial-d accumulation order as before
  float acck = bk[t], accv = bv[t];
  for (int d = 0; d < DM; ++d) {
    const float f = vrow[d];
    acck += f * Wk[d*DM + t];
    accv += f * Wv[d*DM + t];
  }
  kpb[bs*DM + t] = acck;
  vpb[bs*DM + t] = accv;
}

// ---------------- 3-NN inverse-distance interpolation + fused q projection ----------------
__global__ void interp_kernel(const float* __restrict__ xyz, const float* __restrict__ new_xyz,
                              const float* __restrict__ v_k, const float* __restrict__ Wq,
                              const float* __restrict__ bq, float* __restrict__ qbuf) {
  const int b = blockIdx.y;
  const int tid = threadIdx.x;            // 256
  const int wave = tid >> 6, lane = tid & 63;
  const int n = blockIdx.x*4 + wave;
  __shared__ float pts[S*3];
  __shared__ float vqs[4][DM];
  for (int i = tid; i < S*3; i += 256) pts[i] = xyz ? new_xyz[b*S*3 + i] : 0.0f;
  __syncthreads();
  const float qx = xyz[(b*N+n)*3+0], qy = xyz[(b*N+n)*3+1], qz = xyz[(b*N+n)*3+2];
  const float qn = qx*qx + qy*qy + qz*qz;
  float d[8];
  #pragma unroll
  for (int j = 0; j < 8; ++j) {
    const int p = j*64 + lane;
    const float px = pts[p*3+0], py = pts[p*3+1], pz = pts[p*3+2];
    const float dot = qx*px + qy*py + qz*pz;
    const float pn  = px*px + py*py + pz*pz;
    d[j] = (-2.0f*dot + qn) + pn;
  }
  unsigned mask = 0xFFu;
  float sd[3]; int sp[3];
  #pragma unroll
  for (int k = 0; k < 3; ++k) {
    float bv = INFINITY; int bj = 0;
    #pragma unroll
    for (int j = 0; j < 8; ++j) {
      if (((mask >> j) & 1u) && d[j] < bv) { bv = d[j]; bj = j; }
    }
    int bp = bj*64 + lane;
    #pragma unroll
    for (int m = 1; m < 64; m <<= 1) {
      const float ov = __shfl_xor(bv, m);
      const int   op = __shfl_xor(bp, m);
      if (ov < bv || (ov == bv && op < bp)) { bv = ov; bp = op; }
    }
    sd[k] = bv; sp[k] = bp;
    if ((bp & 63) == lane) mask &= ~(1u << (bp >> 6));
  }
  float w0 = 1.0f / fmaxf(sd[0], 1e-10f);
  float w1 = 1.0f / fmaxf(sd[1], 1e-10f);
  float w2 = 1.0f / fmaxf(sd[2], 1e-10f);
  const float wsum = w0 + w1 + w2;
  w0 /= wsum; w1 /= wsum; w2 /= wsum;
  const float* vk0 = v_k + (b*S + sp[0])*DM;
  const float* vk1 = v_k + (b*S + sp[1])*DM;
  const float* vk2 = v_k + (b*S + sp[2])*DM;
  #pragma unroll
  for (int c = lane; c < DM; c += 64) {
    vqs[wave][c] = w0*vk0[c] + w1*vk1[c] + w2*vk2[c];
  }
  __syncthreads();
  // fused q projection: each lane owns channels lane and lane+64 of its wave's row
  const float* row = vqs[wave];
  #pragma unroll
  for (int half = 0; half < 2; ++half) {
    const int c = lane + half*64;
    float acc = bq[c];
    for (int d = 0; d < DM; ++d) acc += row[d] * Wq[d*DM + c];
    qbuf[(b*N+n)*DM + c] = acc;
  }
}

// ---------------- cross-attention (RPE MLP fused, r4 inner) + output projection ----------------
__global__ void attn_kernel(const float* __restrict__ xyz, const float* __restrict__ new_xyz,
                            const float* __restrict__ qb, const float* __restrict__ kp,
                            const float* __restrict__ vp, const float* __restrict__ Wp1,
                            const float* __restrict__ bp1, const float* __restrict__ Wp2,
                            const float* __restrict__ bp2, const float* __restrict__ Wo,
                            const float* __restrict__ bo, float* __restrict__ out) {
  const int bn = blockIdx.x;              // b*N + n
  const int b = bn / N;
  const int t = threadIdx.x;              // 128
  __shared__ __align__(16) float e[NH][EPAD];
  __shared__ float qn_s[DM];
  __shared__ float oa[DM];
  __shared__ float ssum[NH];
  qn_s[t] = qb[bn*DM + t];
  __syncthreads();
  const float qx = xyz[bn*3+0], qy = xyz[bn*3+1], qz = xyz[bn*3+2];
  const float rs = 0.17677669529663687f;  // 1/sqrt(32)
  for (int j = t; j < S; j += 128) {
    const float px = new_xyz[(b*S+j)*3+0], py = new_xyz[(b*S+j)*3+1], pz = new_xyz[(b*S+j)*3+2];
    const float rx = qx-px, ry = qy-py, rz = qz-pz;
    float r0 = bp2[0], r1 = bp2[1], r2 = bp2[2], r3 = bp2[3];
    for (int m = 0; m < DM; ++m) {
      float hm = rx*Wp1[m] + ry*Wp1[DM+m] + rz*Wp1[2*DM+m] + bp1[m];
      hm = fmaxf(hm, 0.0f);
      r0 += hm*Wp2[m*NH+0]; r1 += hm*Wp2[m*NH+1];
      r2 += hm*Wp2[m*NH+2]; r3 += hm*Wp2[m*NH+3];
    }
    const float rpe[NH] = {r0, r1, r2, r3};
    #pragma unroll
    for (int h = 0; h < NH; ++h) {
      const float* kr = kp + (b*S+j)*DM + h*DH;
      const float* qr = qn_s + h*DH;
      float acc = 0.0f;
      #pragma unroll
      for (int dd = 0; dd < DH; ++dd) acc += qr[dd]*kr[dd];
      e[h][j] = acc*rs + rpe[h];
    }
  }
  __syncthreads();
  const int h = t >> 5, g = t & 31;       // 32 threads per head
  float mx = -INFINITY;
  for (int j = g; j < S; j += 32) mx = fmaxf(mx, e[h][j]);
  #pragma unroll
  for (int m = 16; m >= 1; m >>= 1) mx = fmaxf(mx, __shfl_xor(mx, m));
  float sum = 0.0f;
  for (int j = g; j < S; j += 32) { const float ex = expf(e[h][j]-mx); e[h][j] = ex; sum += ex; }
  #pragma unroll
  for (int m = 16; m >= 1; m >>= 1) sum += __shfl_xor(sum, m);
  if (g == 0) ssum[h] = sum;
  __syncthreads();
  float acc = 0.0f;
  for (int j = 0; j < S; j += 4) {
    const float4 ev = *reinterpret_cast<const float4*>(&e[h][j]);
    acc += ev.x * vp[(b*S+j+0)*DM + t];
    acc += ev.y * vp[(b*S+j+1)*DM + t];
    acc += ev.z * vp[(b*S+j+2)*DM + t];
    acc += ev.w * vp[(b*S+j+3)*DM + t];
  }
  oa[t] = acc / ssum[h];
  __syncthreads();
  float facc = bo[t];
  for (int d = 0; d < DM; ++d) facc += oa[d] * Wo[d*DM + t];
  out[bn*DM + t] = facc;
}

}  // namespace

extern "C" void kernel_launch(void* const* d_in, const int* in_sizes, int n_in,
                              void* d_out, int out_size, void* d_ws, size_t ws_size,
                              hipStream_t stream) {
  const float* xyz   = (const float*)d_in[0];
  const float* feats = (const float*)d_in[1];
  const float* alpha = (const float*)d_in[2];
  const float* beta  = (const float*)d_in[3];
  const float* W_t   = (const float*)d_in[4];
  const float* b_t   = (const float*)d_in[5];
  const float* bn_g  = (const float*)d_in[6];
  const float* bn_b  = (const float*)d_in[7];
  const float* Wq = (const float*)d_in[8];  const float* bq = (const float*)d_in[9];
  const float* Wk = (const float*)d_in[10]; const float* bk = (const float*)d_in[11];
  const float* Wv = (const float*)d_in[12]; const float* bv = (const float*)d_in[13];
  const float* Wo = (const float*)d_in[14]; const float* bo = (const float*)d_in[15];
  const float* Wp1= (const float*)d_in[16]; const float* bp1= (const float*)d_in[17];
  const float* Wp2= (const float*)d_in[18]; const float* bp2= (const float*)d_in[19];

  char* w = (char*)d_ws;
  int*    fps_i = (int*)   (w + 0);        // B*S ints            (4 KB)
  float*  nxyz  = (float*) (w + 4096);     // B*S*3               (12 KB)
  int*    knn_i = (int*)   (w + 16384);    // B*S*K ints          (128 KB)
  float*  meanb = (float*) (w + 147456);   // B*S*GC              (268 KB)
  float2* part  = (float2*)(w + 421888);   // B*S float2          (8 KB)
  float*  invs  = (float*) (w + 430080);   // B floats
  float*  vk    = (float*) (w + 430336);   // B*S*DM              (512 KB)
  float*  qbuf  = (float*) (w + 2003200);  // B*N*DM              (1 MB)
  float*  kpb   = (float*) (w + 3051776);  // B*S*DM              (512 KB)
  float*  vpb   = (float*) (w + 3576064);  // B*S*DM              (512 KB)
  float*  outf  = (float*)d_out;

  fps_kernel<<<B, 64, 0, stream>>>(xyz, fps_i, nxyz);
  knn_kernel<<<dim3(S/4, B), 256, 0, stream>>>(xyz, nxyz, knn_i);
  group_stats_kernel<<<B*S, 128, 0, stream>>>(feats, xyz, knn_i, meanb, part);
  stats_kernel<<<B, 64, 0, stream>>>(part, invs);
  transfer_kernel<<<B*S, 128, 0, stream>>>(feats, xyz, knn_i, fps_i, meanb, invs,
                                           alpha, beta, W_t, b_t, bn_g, bn_b,
                                           Wk, bk, Wv, bv, vk, kpb, vpb);
  interp_kernel<<<dim3(N/4, B), 256, 0, stream>>>(xyz, nxyz, vk, Wq, bq, qbuf);
  attn_kernel<<<B*N, 128, 0, stream>>>(xyz, nxyz, qbuf, kpb, vpb, Wp1, bp1, Wp2, bp2, Wo, bo, outf);
}